// Round 4
// baseline (2367.922 us; speedup 1.0000x reference)
//
#include <hip/hip_runtime.h>

// ---------------------------------------------------------------------------
// Bidirectional GRU (B=128, T=512, E=H=256) + linear head.
// Phase 1 (R16 = R14): gate table, per-thread-contiguous 48 B chunks:
//   chunk = ((d*8+w)*4+q)*24, slots: xr:8l, xz:8l+4, xn:16+4l, +r.
// Phase 2 (R16): R15's depth-2 register prefetch, but with
//   __launch_bounds__(512, 1): R15's (512,2) capped VGPRs at 128 and the
//   second prefetch set SPILLED to scratch (32 ms first-dispatch scratch
//   alloc outlier; scratch reloads in the vmcnt queue re-serialized every
//   step). Grid is 16 blocks on 256 CUs -> 1 block/CU; the 128-cap bought
//   zero occupancy. Everything else identical to R15.
// ---------------------------------------------------------------------------

typedef float f32x4 __attribute__((ext_vector_type(4)));
typedef short s16x8 __attribute__((ext_vector_type(8)));

#define VOCAB   30000
#define GCOLS   1536
#define HB_STR  280     // bf16 elems per h/emb row (560 B)
#define HBUF    (16 * HB_STR)
#define HS_STR  260     // f32 elems per h row for epilogue
#define SRF     (-1.4426950408889634f)   // -log2(e), sigmoid gates
#define SNF     (2.8853900817779268f)    // 2*log2(e), tanh gate

#if defined(__has_builtin)
#if __has_builtin(__builtin_amdgcn_cvt_pk_bf16_f32)
#define HAVE_PK 1
#endif
#endif

static __device__ __forceinline__ unsigned short f2bf(float f) {
    unsigned u = __builtin_bit_cast(unsigned, f);
    u += 0x7fffu + ((u >> 16) & 1u);            // RNE
    return (unsigned short)(u >> 16);
}
#ifdef HAVE_PK
typedef __bf16 bf16x2_t __attribute__((ext_vector_type(2)));
static __device__ __forceinline__ unsigned pk2(float a, float b) {
    bf16x2_t v = __builtin_amdgcn_cvt_pk_bf16_f32(a, b);
    return __builtin_bit_cast(unsigned, v);
}
#else
static __device__ __forceinline__ unsigned pk2(float a, float b) {
    return (unsigned)f2bf(a) | ((unsigned)f2bf(b) << 16);
}
#endif
static __device__ __forceinline__ float bf_lo(unsigned v) {
    return __builtin_bit_cast(float, v << 16);
}
static __device__ __forceinline__ float bf_hi(unsigned v) {
    return __builtin_bit_cast(float, v & 0xffff0000u);
}
static __device__ __forceinline__ s16x8 pack_bf8(float4 a, float4 b, float s) {
    union { s16x8 v; unsigned u[4]; } r;
    r.u[0] = pk2(a.x * s, a.y * s); r.u[1] = pk2(a.z * s, a.w * s);
    r.u[2] = pk2(b.x * s, b.y * s); r.u[3] = pk2(b.z * s, b.w * s);
    return r.v;
}
static __device__ __forceinline__ f32x4 mfma16(s16x8 a, s16x8 b, f32x4 c) {
    return __builtin_amdgcn_mfma_f32_16x16x32_bf16(a, b, c, 0, 0, 0);
}
static __device__ __forceinline__ float sig2(float x) {      // 1/(1+2^x)
    return __builtin_amdgcn_rcpf(1.0f + __builtin_amdgcn_exp2f(x));
}
// Raw barrier that drains ONLY lgkmcnt (h-exchange LDS traffic); global
// gather loads issued earlier stay in flight across it.
static __device__ __forceinline__ void lgkm_barrier() {
    __builtin_amdgcn_sched_barrier(0);
    asm volatile("s_waitcnt lgkmcnt(0)" ::: "memory");
    __builtin_amdgcn_sched_barrier(0);
    __builtin_amdgcn_s_barrier();
    __builtin_amdgcn_sched_barrier(0);
}

// ---------------------------------------------------------------------------
// Phase 1: gate table.  grid (2 dirs, 128 M-slices), 512 threads.
// G layout (per token row of 1536 bf16):
//   chunk = ((d*8 + w)*4 + (u>>2))*24,  in-chunk = slot + (u&3)
//   slot: r-gate half l -> 8*l ; z-gate -> 8*l+4 ; n-gate -> 16 + 4*l
// so consumer thread (d,w,q) reads [xr0 xz0][xr1 xz1][xn0 xn1] = 3 dwordx4.
// ---------------------------------------------------------------------------
__global__ __launch_bounds__(512, 2)
void gru_table_kernel(const float* __restrict__ emb,
                      const float* __restrict__ Wih_f, const float* __restrict__ bih_f,
                      const float* __restrict__ bhh_f,
                      const float* __restrict__ Wih_b, const float* __restrict__ bih_b,
                      const float* __restrict__ bhh_b,
                      unsigned short* __restrict__ G) {
    __shared__ unsigned short aS[2][16 * HB_STR];    // dbuf emb tile (bf16)

    const int tid  = threadIdx.x;
    const int lane = tid & 63;
    const int w    = tid >> 6;       // wave 0..7
    const int u    = lane & 15;
    const int q    = lane >> 4;
    const int d    = blockIdx.x;     // 0 fwd, 1 bwd
    const int by   = blockIdx.y;     // 0..127

    const float* Wih = d ? Wih_b : Wih_f;
    const float* bih = d ? bih_b : bih_f;
    const float* bhh = d ? bhh_b : bhh_f;

    s16x8 breg[48];
    float beta[6];
#pragma unroll
    for (int t = 0; t < 6; ++t) {
        const int orig = (t >> 1) * 256 + 32 * w + ((t & 1) << 4) + u;
        const float scl = (t < 4) ? SRF : SNF;
        beta[t] = (bih[orig] + ((t < 4) ? bhh[orig] : 0.0f)) * scl;
#pragma unroll
        for (int kt = 0; kt < 8; ++kt) {
            const float* p = Wih + orig * 256 + kt * 32 + q * 8;
            breg[t * 8 + kt] =
                pack_bf8(*(const float4*)p, *(const float4*)(p + 4), scl);
        }
    }

    const int srow = tid >> 5;
    const int sc8  = (tid & 31) * 8;

    {
        const float* p = emb + (size_t)(by * 16 + srow) * 256 + sc8;
        float4 e0 = *(const float4*)p, e1 = *(const float4*)(p + 4);
        unsigned* dp = (unsigned*)&aS[0][srow * HB_STR + sc8];
        dp[0] = pk2(e0.x, e0.y); dp[1] = pk2(e0.z, e0.w);
        dp[2] = pk2(e1.x, e1.y); dp[3] = pk2(e1.z, e1.w);
    }
    __syncthreads();

    const int ubase = ((d * 8 + w) * 4 + (u >> 2)) * 24 + (u & 3);

    for (int i = 0;; ++i) {
        const int mt = by + i * 128;
        if (mt >= 1875) break;
        const int mtn = mt + 128;
        const bool has_next = (mtn < 1875);
        const int buf = i & 1;

        float4 e0, e1;
        if (has_next) {
            const float* p = emb + (size_t)(mtn * 16 + srow) * 256 + sc8;
            e0 = *(const float4*)p;
            e1 = *(const float4*)(p + 4);
        }

        const int v0 = mt * 16;
#pragma unroll
        for (int l = 0; l < 2; ++l) {
            f32x4 a0 = {0.f, 0.f, 0.f, 0.f}, a1 = a0, a2 = a0;
#pragma unroll
            for (int kt = 0; kt < 8; ++kt) {
                s16x8 af = *(const s16x8*)&aS[buf][u * HB_STR + kt * 32 + q * 8];
                a0 = mfma16(af, breg[(0 + l) * 8 + kt], a0);
                a1 = mfma16(af, breg[(2 + l) * 8 + kt], a1);
                a2 = mfma16(af, breg[(4 + l) * 8 + kt], a2);
            }
#pragma unroll
            for (int g = 0; g < 3; ++g) {
                const f32x4 a = (g == 0) ? a0 : (g == 1) ? a1 : a2;
                const int t    = 2 * g + l;
                const int slot = (g < 2) ? (8 * l + 4 * g) : (16 + 4 * l);
                unsigned short* gp =
                    G + (size_t)(v0 + q * 4) * GCOLS + ubase + slot;
#pragma unroll
                for (int r = 0; r < 4; ++r)
                    gp[(size_t)r * GCOLS] = f2bf(a[r] + beta[t]);
            }
        }
        if (has_next) {
            unsigned* dp = (unsigned*)&aS[buf ^ 1][srow * HB_STR + sc8];
            dp[0] = pk2(e0.x, e0.y); dp[1] = pk2(e0.z, e0.w);
            dp[2] = pk2(e1.x, e1.y); dp[3] = pk2(e1.z, e1.w);
        }
        __syncthreads();
    }
}

// ---------------------------------------------------------------------------
// Phase 2: recurrence. grid = 16 (dir = bx>>3, batch group = bx&7), 512 thr.
// Depth-2 register prefetch of xg; lgkm-only barrier; xr/xz as acc-inits.
// ---------------------------------------------------------------------------

// One GRU step. Reads h from hB[RB+...], writes h_new to hB[WB+...].
// Consumes prefetched set (PA,PB,PN) (issued 2 steps ago), then reloads the
// same registers with step SP's gate data (clamped; redundant tail loads ok).
#define GRU_STEP(RB, WB, PA, PB, PN, SP)                                      \
    {                                                                         \
        f32x4 arI0 = {bf_lo(PA.x), bf_hi(PA.x), bf_lo(PA.y), bf_hi(PA.y)};    \
        f32x4 azI0 = {bf_lo(PA.z), bf_hi(PA.z), bf_lo(PA.w), bf_hi(PA.w)};    \
        f32x4 arI1 = {bf_lo(PB.x), bf_hi(PB.x), bf_lo(PB.y), bf_hi(PB.y)};    \
        f32x4 azI1 = {bf_lo(PB.z), bf_hi(PB.z), bf_lo(PB.w), bf_hi(PB.w)};    \
        const uint4 nn = PN;                                                  \
        {                                                                     \
            const int s2 = ((SP) < 511) ? (SP) : 511;                         \
            const int tt = d ? 511 - s2 : s2;                                 \
            const unsigned short* gb = Gt + (size_t)toks[b][tt] * GCOLS;      \
            PA = *(const uint4*)(gb);                                         \
            PB = *(const uint4*)(gb + 8);                                     \
            PN = *(const uint4*)(gb + 16);                                    \
        }                                                                     \
        _Pragma("unroll")                                                     \
        for (int l = 0; l < 2; ++l) {                                         \
            f32x4 ar = l ? arI1 : arI0;                                       \
            f32x4 az = l ? azI1 : azI0;                                       \
            __builtin_amdgcn_s_setprio(1);                                    \
            _Pragma("unroll")                                                 \
            for (int kt = 0; kt < 8; ++kt) {                                  \
                s16x8 hf = *(const s16x8*)&hB[(RB) + hbq + kt * 32];          \
                ar = mfma16(wreg[(0 + l) * 8 + kt], hf, ar);                  \
                az = mfma16(wreg[(2 + l) * 8 + kt], hf, az);                  \
            }                                                                 \
            f32x4 an = *(const f32x4*)&bhnS[32 * w + 16 * l + 4 * q];         \
            _Pragma("unroll")                                                 \
            for (int kt = 0; kt < 8; ++kt) {                                  \
                s16x8 hf = *(const s16x8*)&hB[(RB) + hbq + kt * 32];          \
                an = mfma16(wreg[(4 + l) * 8 + kt], hf, an);                  \
            }                                                                 \
            __builtin_amdgcn_s_setprio(0);                                    \
            float rg[4], zg[4];                                               \
            _Pragma("unroll")                                                 \
            for (int r = 0; r < 4; ++r) {                                     \
                rg[r] = sig2(ar[r]);                                          \
                zg[r] = sig2(az[r]);                                          \
            }                                                                 \
            const unsigned nx0 = l ? nn.z : nn.x;                             \
            const unsigned nx1 = l ? nn.w : nn.y;                             \
            const float xn[4] = {bf_lo(nx0), bf_hi(nx0),                      \
                                 bf_lo(nx1), bf_hi(nx1)};                     \
            _Pragma("unroll")                                                 \
            for (int r = 0; r < 4; ++r) {                                     \
                float tg = sig2(fmaf(rg[r], an[r], xn[r]));                   \
                float ng = fmaf(-2.0f, tg, 1.0f);                             \
                const int i = l * 4 + r;                                      \
                hreg[i] = fmaf(zg[r], hreg[i] - ng, ng);                      \
            }                                                                 \
            unsigned h0 = pk2(hreg[l * 4 + 0], hreg[l * 4 + 1]);              \
            unsigned h1 = pk2(hreg[l * 4 + 2], hreg[l * 4 + 3]);              \
            *(uint2*)&hB[(WB) + b * HB_STR + 32 * w + 16 * l + 4 * q] =       \
                make_uint2(h0, h1);                                           \
        }                                                                     \
    }

__global__ __launch_bounds__(512, 1)
void gru_rnn_kernel(const int* __restrict__ inp,
                    const float* __restrict__ Whh_f, const float* __restrict__ bhh_f,
                    const float* __restrict__ Whh_b, const float* __restrict__ bhh_b,
                    const float* __restrict__ W_lin, const float* __restrict__ b_lin,
                    const unsigned short* __restrict__ G,
                    float* __restrict__ out) {
    __shared__ int            toks[16][513];          // 32.8 KB
    __shared__ unsigned short hB[2 * HBUF];           // 17.9 KB dbuf h (bf16)
    __shared__ float          bhnS[256];              // 1 KB
    __shared__ float          hs[16 * HS_STR];        // 16.6 KB epilogue

    const int tid  = threadIdx.x;
    const int lane = tid & 63;
    const int w    = tid >> 6;          // wave 0..7 (owns cols [32w,32w+32))
    const int b    = lane & 15;         // batch within group
    const int q    = lane >> 4;
    const int d    = blockIdx.x >> 3;   // 0 fwd, 1 bwd
    const int b0   = (blockIdx.x & 7) * 16;

    const float* Whh = d ? Whh_b : Whh_f;
    const float* bhh = d ? bhh_b : bhh_f;

    // W_hh as 48 A-fragments (pre-scaled): tile t = 2*gate + half.
    s16x8 wreg[48];
#pragma unroll
    for (int t = 0; t < 6; ++t) {
        const int orig = (t >> 1) * 256 + 32 * w + ((t & 1) << 4) + b;
        const float scl = (t < 4) ? SRF : SNF;
#pragma unroll
        for (int kt = 0; kt < 8; ++kt) {
            const float* p = Whh + orig * 256 + kt * 32 + q * 8;
            wreg[t * 8 + kt] =
                pack_bf8(*(const float4*)p, *(const float4*)(p + 4), scl);
        }
    }

    for (int i = tid; i < 16 * 512; i += 512) {
        int bb = i >> 9, t = i & 511;
        toks[bb][t] = inp[(b0 + bb) * 512 + t];
    }
    for (int i = tid; i < 2 * HBUF; i += 512) hB[i] = 0;   // h0 = 0
    if (tid < 256) bhnS[tid] = SNF * bhh[512 + tid];
    __syncthreads();

    const int hbq = b * HB_STR + q * 8;
    // this thread's 48 B gate-chunk base inside a token row
    const unsigned short* Gt = G + (size_t)(((d * 8 + w) * 4 + q) * 24);

    float hreg[8];
#pragma unroll
    for (int i = 0; i < 8; ++i) hreg[i] = 0.f;

    // prologue: prefetch xg for steps 0 (pa*) and 1 (pb*)
    uint4 pa0, pa1, pa2, pb0, pb1, pb2;
    {
        const int t0 = d ? 511 : 0;
        const unsigned short* g0 = Gt + (size_t)toks[b][t0] * GCOLS;
        pa0 = *(const uint4*)(g0);
        pa1 = *(const uint4*)(g0 + 8);
        pa2 = *(const uint4*)(g0 + 16);
        const int t1 = d ? 510 : 1;
        const unsigned short* g1 = Gt + (size_t)toks[b][t1] * GCOLS;
        pb0 = *(const uint4*)(g1);
        pb1 = *(const uint4*)(g1 + 8);
        pb2 = *(const uint4*)(g1 + 16);
    }

    for (int ts = 0; ts < 512; ts += 2) {
        // even step: h in hB[0..], h_new -> hB[HBUF..]; prefetch step ts+2
        GRU_STEP(0, HBUF, pa0, pa1, pa2, ts + 2);
        lgkm_barrier();
        // odd step: h in hB[HBUF..], h_new -> hB[0..]; prefetch step ts+3
        GRU_STEP(HBUF, 0, pb0, pb1, pb2, ts + 3);
        lgkm_barrier();
    }

    // epilogue: out[b][c] += h_d[b] . W_lin[c, d*256:+256]  (+ b_lin once)
#pragma unroll
    for (int l = 0; l < 2; ++l) {
        f32x4 v = {hreg[l * 4 + 0], hreg[l * 4 + 1],
                   hreg[l * 4 + 2], hreg[l * 4 + 3]};
        *(f32x4*)&hs[b * HS_STR + 32 * w + 16 * l + 4 * q] = v;
    }
    __syncthreads();
    if (tid < 160) {
        int bb = tid / 10;
        int c  = tid - bb * 10;
        float acc = d ? 0.0f : b_lin[c];
        const float* wl = W_lin + c * 512 + d * 256;
        const float* hp = &hs[bb * HS_STR];
        for (int i = 0; i < 256; ++i) acc += hp[i] * wl[i];
        atomicAdd(&out[(b0 + bb) * 10 + c], acc);
    }
}

// ---------------------------------------------------------------------------
extern "C" void kernel_launch(void* const* d_in, const int* in_sizes, int n_in,
                              void* d_out, int out_size, void* d_ws, size_t ws_size,
                              hipStream_t stream) {
    const int*   inp   = (const int*)d_in[0];
    const float* emb   = (const float*)d_in[1];
    const float* Wih_f = (const float*)d_in[2];
    const float* Whh_f = (const float*)d_in[3];
    const float* bih_f = (const float*)d_in[4];
    const float* bhh_f = (const float*)d_in[5];
    const float* Wih_b = (const float*)d_in[6];
    const float* Whh_b = (const float*)d_in[7];
    const float* bih_b = (const float*)d_in[8];
    const float* bhh_b = (const float*)d_in[9];
    const float* W_lin = (const float*)d_in[10];
    const float* b_lin = (const float*)d_in[11];
    float* out = (float*)d_out;
    unsigned short* G = (unsigned short*)d_ws;   // 30000*1536*2 B = 92.16 MB

    hipMemsetAsync(d_out, 0, (size_t)out_size * sizeof(float), stream);
    hipLaunchKernelGGL(gru_table_kernel, dim3(2, 128), dim3(512), 0, stream,
                       emb, Wih_f, bih_f, bhh_f, Wih_b, bih_b, bhh_b, G);
    hipLaunchKernelGGL(gru_rnn_kernel, dim3(16), dim3(512), 0, stream,
                       inp, Whh_f, bhh_f, Whh_b, bhh_b, W_lin, b_lin, G, out);
}

// Round 5
// 1900.997 us; speedup vs baseline: 1.2456x; 1.2456x over previous
//
#include <hip/hip_runtime.h>

// ---------------------------------------------------------------------------
// Bidirectional GRU (B=128, T=512, E=H=256) + linear head.
// Phase 1 (R17 = R16/R14, verified): gate table, per-thread 48 B chunks:
//   elem = d*768 + (w*4+q)*24 + slot + r; slot: xr0:0 xz0:4 xr1:8 xz1:12
//   xn0:16 xn1:20.  Each dir-half of a token row is contiguous 1536 B.
// Phase 2 (R17): 4-deep LDS ring, distance-2 staging via global_load_lds
//   (3x 1KB per wave per step), counted drain vmcnt(3) at the barrier
//   (never 0): waits only on loads issued 2 steps ago => ~2 steps of
//   latency cover, cross-wave validity via the barrier (T3/T4 pattern).
//   Ring rows XOR-swizzled (byte ^ ((row&7)<<4)) against the 16-way
//   bank conflict; swizzle applied as pre-swizzled global SOURCE on the
//   staging side (linear LDS dest, rule 21) and on the ds_read address.
//   Consumer decode identical to R14 (xr/xz fold into MFMA acc-init).
// ---------------------------------------------------------------------------

typedef float f32x4 __attribute__((ext_vector_type(4)));
typedef short s16x8 __attribute__((ext_vector_type(8)));

#define VOCAB   30000
#define GCOLS   1536
#define HB_STR  280     // bf16 elems per h/emb row (560 B)
#define HBUF    (16 * HB_STR)
#define HS_STR  260     // f32 elems per h row for epilogue
#define XG_ROW  768     // bf16 elems per ring row (one dir-half)
#define XG_SLOT (16 * XG_ROW)
#define SRF     (-1.4426950408889634f)   // -log2(e), sigmoid gates
#define SNF     (2.8853900817779268f)    // 2*log2(e), tanh gate

#if defined(__has_builtin)
#if __has_builtin(__builtin_amdgcn_cvt_pk_bf16_f32)
#define HAVE_PK 1
#endif
#endif

static __device__ __forceinline__ unsigned short f2bf(float f) {
    unsigned u = __builtin_bit_cast(unsigned, f);
    u += 0x7fffu + ((u >> 16) & 1u);            // RNE
    return (unsigned short)(u >> 16);
}
#ifdef HAVE_PK
typedef __bf16 bf16x2_t __attribute__((ext_vector_type(2)));
static __device__ __forceinline__ unsigned pk2(float a, float b) {
    bf16x2_t v = __builtin_amdgcn_cvt_pk_bf16_f32(a, b);
    return __builtin_bit_cast(unsigned, v);
}
#else
static __device__ __forceinline__ unsigned pk2(float a, float b) {
    return (unsigned)f2bf(a) | ((unsigned)f2bf(b) << 16);
}
#endif
static __device__ __forceinline__ float bf_lo(unsigned v) {
    return __builtin_bit_cast(float, v << 16);
}
static __device__ __forceinline__ float bf_hi(unsigned v) {
    return __builtin_bit_cast(float, v & 0xffff0000u);
}
static __device__ __forceinline__ s16x8 pack_bf8(float4 a, float4 b, float s) {
    union { s16x8 v; unsigned u[4]; } r;
    r.u[0] = pk2(a.x * s, a.y * s); r.u[1] = pk2(a.z * s, a.w * s);
    r.u[2] = pk2(b.x * s, b.y * s); r.u[3] = pk2(b.z * s, b.w * s);
    return r.v;
}
static __device__ __forceinline__ f32x4 mfma16(s16x8 a, s16x8 b, f32x4 c) {
    return __builtin_amdgcn_mfma_f32_16x16x32_bf16(a, b, c, 0, 0, 0);
}
static __device__ __forceinline__ float sig2(float x) {      // 1/(1+2^x)
    return __builtin_amdgcn_rcpf(1.0f + __builtin_amdgcn_exp2f(x));
}
static __device__ __forceinline__ void gload_lds16(const unsigned short* g, unsigned short* l) {
    __builtin_amdgcn_global_load_lds(
        (const __attribute__((address_space(1))) unsigned*)g,
        (__attribute__((address_space(3))) unsigned*)l, 16, 0, 0);
}
// Counted drain: wait only for loads issued >=2 steps ago (3 newest stay in
// flight), drain LDS ops, then barrier. vmcnt never 0 in the main loop.
static __device__ __forceinline__ void step_barrier_v3() {
    __builtin_amdgcn_sched_barrier(0);
    asm volatile("s_waitcnt vmcnt(3) lgkmcnt(0)" ::: "memory");
    __builtin_amdgcn_sched_barrier(0);
    __builtin_amdgcn_s_barrier();
    __builtin_amdgcn_sched_barrier(0);
}

// ---------------------------------------------------------------------------
// Phase 1: gate table (verified, unchanged from R16).
// ---------------------------------------------------------------------------
__global__ __launch_bounds__(512, 2)
void gru_table_kernel(const float* __restrict__ emb,
                      const float* __restrict__ Wih_f, const float* __restrict__ bih_f,
                      const float* __restrict__ bhh_f,
                      const float* __restrict__ Wih_b, const float* __restrict__ bih_b,
                      const float* __restrict__ bhh_b,
                      unsigned short* __restrict__ G) {
    __shared__ unsigned short aS[2][16 * HB_STR];    // dbuf emb tile (bf16)

    const int tid  = threadIdx.x;
    const int lane = tid & 63;
    const int w    = tid >> 6;       // wave 0..7
    const int u    = lane & 15;
    const int q    = lane >> 4;
    const int d    = blockIdx.x;     // 0 fwd, 1 bwd
    const int by   = blockIdx.y;     // 0..127

    const float* Wih = d ? Wih_b : Wih_f;
    const float* bih = d ? bih_b : bih_f;
    const float* bhh = d ? bhh_b : bhh_f;

    s16x8 breg[48];
    float beta[6];
#pragma unroll
    for (int t = 0; t < 6; ++t) {
        const int orig = (t >> 1) * 256 + 32 * w + ((t & 1) << 4) + u;
        const float scl = (t < 4) ? SRF : SNF;
        beta[t] = (bih[orig] + ((t < 4) ? bhh[orig] : 0.0f)) * scl;
#pragma unroll
        for (int kt = 0; kt < 8; ++kt) {
            const float* p = Wih + orig * 256 + kt * 32 + q * 8;
            breg[t * 8 + kt] =
                pack_bf8(*(const float4*)p, *(const float4*)(p + 4), scl);
        }
    }

    const int srow = tid >> 5;
    const int sc8  = (tid & 31) * 8;

    {
        const float* p = emb + (size_t)(by * 16 + srow) * 256 + sc8;
        float4 e0 = *(const float4*)p, e1 = *(const float4*)(p + 4);
        unsigned* dp = (unsigned*)&aS[0][srow * HB_STR + sc8];
        dp[0] = pk2(e0.x, e0.y); dp[1] = pk2(e0.z, e0.w);
        dp[2] = pk2(e1.x, e1.y); dp[3] = pk2(e1.z, e1.w);
    }
    __syncthreads();

    const int ubase = ((d * 8 + w) * 4 + (u >> 2)) * 24 + (u & 3);

    for (int i = 0;; ++i) {
        const int mt = by + i * 128;
        if (mt >= 1875) break;
        const int mtn = mt + 128;
        const bool has_next = (mtn < 1875);
        const int buf = i & 1;

        float4 e0, e1;
        if (has_next) {
            const float* p = emb + (size_t)(mtn * 16 + srow) * 256 + sc8;
            e0 = *(const float4*)p;
            e1 = *(const float4*)(p + 4);
        }

        const int v0 = mt * 16;
#pragma unroll
        for (int l = 0; l < 2; ++l) {
            f32x4 a0 = {0.f, 0.f, 0.f, 0.f}, a1 = a0, a2 = a0;
#pragma unroll
            for (int kt = 0; kt < 8; ++kt) {
                s16x8 af = *(const s16x8*)&aS[buf][u * HB_STR + kt * 32 + q * 8];
                a0 = mfma16(af, breg[(0 + l) * 8 + kt], a0);
                a1 = mfma16(af, breg[(2 + l) * 8 + kt], a1);
                a2 = mfma16(af, breg[(4 + l) * 8 + kt], a2);
            }
#pragma unroll
            for (int g = 0; g < 3; ++g) {
                const f32x4 a = (g == 0) ? a0 : (g == 1) ? a1 : a2;
                const int t    = 2 * g + l;
                const int slot = (g < 2) ? (8 * l + 4 * g) : (16 + 4 * l);
                unsigned short* gp =
                    G + (size_t)(v0 + q * 4) * GCOLS + ubase + slot;
#pragma unroll
                for (int r = 0; r < 4; ++r)
                    gp[(size_t)r * GCOLS] = f2bf(a[r] + beta[t]);
            }
        }
        if (has_next) {
            unsigned* dp = (unsigned*)&aS[buf ^ 1][srow * HB_STR + sc8];
            dp[0] = pk2(e0.x, e0.y); dp[1] = pk2(e0.z, e0.w);
            dp[2] = pk2(e1.x, e1.y); dp[3] = pk2(e1.z, e1.w);
        }
        __syncthreads();
    }
}

// ---------------------------------------------------------------------------
// Phase 2: recurrence. grid = 16 (dir = bx>>3, batch group = bx&7), 512 thr.
// 4-deep LDS ring + distance-2 global_load_lds staging + counted vmcnt.
// ---------------------------------------------------------------------------

// Stage step SP's 16 dir-half rows into ring slot SLOT. Wave w stages batch
// rows 2w, 2w+1 (3 KB) as 3x 1KB linear-dest loads; per-lane SOURCE is
// pre-swizzled with the row XOR mask so reads can de-swizzle.
#define STAGE(SLOT, SP)                                                       \
    {                                                                         \
        const int s_  = ((SP) < 511) ? (SP) : 511;                            \
        const int tt_ = d ? 511 - s_ : s_;                                    \
        const unsigned tokA = toksS[2 * w][tt_];                              \
        const unsigned tokB = toksS[2 * w + 1][tt_];                          \
        _Pragma("unroll")                                                     \
        for (int k = 0; k < 3; ++k) {                                         \
            const int Din   = k * 1024 + lane * 16;      /* byte in 3KB */    \
            const int row   = (Din >= 1536) ? 1 : 0;                          \
            const int inner = Din - row * 1536;                               \
            const unsigned tok = row ? tokB : tokA;                           \
            const int msk = ((2 * w + row) & 7) << 4;                         \
            const unsigned short* src =                                       \
                G + (size_t)tok * GCOLS + d * 768 + ((inner ^ msk) >> 1);     \
            gload_lds16(src, &xgR[SLOT][w * 1536 + k * 512]);                 \
        }                                                                     \
    }

__global__ __launch_bounds__(512, 1)
void gru_rnn_kernel(const int* __restrict__ inp,
                    const float* __restrict__ Whh_f, const float* __restrict__ bhh_f,
                    const float* __restrict__ Whh_b, const float* __restrict__ bhh_b,
                    const float* __restrict__ W_lin, const float* __restrict__ b_lin,
                    const unsigned short* __restrict__ G,
                    float* __restrict__ out) {
    __shared__ unsigned short toksS[16][520];         // 16.6 KB (u16 tokens)
    __shared__ unsigned short xgR[4][XG_SLOT];        // 98.3 KB xg ring
    __shared__ unsigned short hB[2 * HBUF];           // 17.9 KB dbuf h (bf16)
    __shared__ float          bhnS[256];              // 1 KB
    __shared__ float          hs[16 * HS_STR];        // 16.6 KB epilogue

    const int tid  = threadIdx.x;
    const int lane = tid & 63;
    const int w    = tid >> 6;          // wave 0..7 (owns cols [32w,32w+32))
    const int b    = lane & 15;         // batch within group
    const int q    = lane >> 4;
    const int d    = blockIdx.x >> 3;   // 0 fwd, 1 bwd
    const int b0   = (blockIdx.x & 7) * 16;

    const float* Whh = d ? Whh_b : Whh_f;
    const float* bhh = d ? bhh_b : bhh_f;

    // W_hh as 48 A-fragments (pre-scaled): tile t = 2*gate + half.
    s16x8 wreg[48];
#pragma unroll
    for (int t = 0; t < 6; ++t) {
        const int orig = (t >> 1) * 256 + 32 * w + ((t & 1) << 4) + b;
        const float scl = (t < 4) ? SRF : SNF;
#pragma unroll
        for (int kt = 0; kt < 8; ++kt) {
            const float* p = Whh + orig * 256 + kt * 32 + q * 8;
            wreg[t * 8 + kt] =
                pack_bf8(*(const float4*)p, *(const float4*)(p + 4), scl);
        }
    }

    for (int i = tid; i < 16 * 512; i += 512) {
        int bb = i >> 9, t = i & 511;
        toksS[bb][t] = (unsigned short)inp[(b0 + bb) * 512 + t];
    }
    for (int i = tid; i < 2 * HBUF; i += 512) hB[i] = 0;   // h0 = 0
    if (tid < 256) bhnS[tid] = SNF * bhh[512 + tid];
    __syncthreads();

    // prologue staging: slot0 <- step0, slot1 <- step1
    STAGE(0, 0);
    STAGE(1, 1);
    __builtin_amdgcn_sched_barrier(0);
    asm volatile("s_waitcnt vmcnt(3)" ::: "memory");   // slot0 complete
    __builtin_amdgcn_sched_barrier(0);
    __builtin_amdgcn_s_barrier();
    __builtin_amdgcn_sched_barrier(0);

    const int hbq = b * HB_STR + q * 8;
    // consumer read offsets (elems) inside a ring slot, de-swizzling rows
    const int cbase = (w * 4 + q) * 48;      // byte offset of chunk in row
    const int bm    = (b & 7) << 4;
    const int xo0 = b * XG_ROW + (((cbase +  0) ^ bm) >> 1);
    const int xo1 = b * XG_ROW + (((cbase + 16) ^ bm) >> 1);
    const int xo2 = b * XG_ROW + (((cbase + 32) ^ bm) >> 1);

    float hreg[8];
#pragma unroll
    for (int i = 0; i < 8; ++i) hreg[i] = 0.f;

#pragma unroll 4
    for (int ts = 0; ts < 512; ++ts) {
        const int rb = (ts & 1) * HBUF;
        const int wb = ((ts + 1) & 1) * HBUF;

        // 1) issue staging for step ts+2 (slot (ts+2)&3; never the consume
        //    slot ts&3). Loads fly across the next two barriers.
        STAGE((ts + 2) & 3, ts + 2);

        // 2) consume this step's xg from ring (ds_read_b128 x3; ready: its
        //    staging retired before the previous barrier's vmcnt(3))
        const unsigned short* xs = &xgR[ts & 3][0];
        const uint4 p0 = *(const uint4*)(xs + xo0);
        const uint4 p1 = *(const uint4*)(xs + xo1);
        const uint4 nn = *(const uint4*)(xs + xo2);
        f32x4 arI0 = {bf_lo(p0.x), bf_hi(p0.x), bf_lo(p0.y), bf_hi(p0.y)};
        f32x4 azI0 = {bf_lo(p0.z), bf_hi(p0.z), bf_lo(p0.w), bf_hi(p0.w)};
        f32x4 arI1 = {bf_lo(p1.x), bf_hi(p1.x), bf_lo(p1.y), bf_hi(p1.y)};
        f32x4 azI1 = {bf_lo(p1.z), bf_hi(p1.z), bf_lo(p1.w), bf_hi(p1.w)};

        // 3) two column-halves, gate-major schedule (R12)
#pragma unroll
        for (int l = 0; l < 2; ++l) {
            f32x4 ar = l ? arI1 : arI0;
            f32x4 az = l ? azI1 : azI0;
            __builtin_amdgcn_s_setprio(1);
            // pass A: r and z gates (16 MFMA, 2 independent chains)
#pragma unroll
            for (int kt = 0; kt < 8; ++kt) {
                s16x8 hf = *(const s16x8*)&hB[rb + hbq + kt * 32];
                ar = mfma16(wreg[(0 + l) * 8 + kt], hf, ar);
                az = mfma16(wreg[(2 + l) * 8 + kt], hf, az);
            }
            // pass B: n gate (8 MFMA) — rg/zg trans overlap its drain
            f32x4 an = *(const f32x4*)&bhnS[32 * w + 16 * l + 4 * q];
#pragma unroll
            for (int kt = 0; kt < 8; ++kt) {
                s16x8 hf = *(const s16x8*)&hB[rb + hbq + kt * 32];
                an = mfma16(wreg[(4 + l) * 8 + kt], hf, an);
            }
            __builtin_amdgcn_s_setprio(0);

            float rg[4], zg[4];
#pragma unroll
            for (int r = 0; r < 4; ++r) {
                rg[r] = sig2(ar[r]);
                zg[r] = sig2(az[r]);
            }
            const unsigned nx0 = l ? nn.z : nn.x;
            const unsigned nx1 = l ? nn.w : nn.y;
            const float xn[4] = {bf_lo(nx0), bf_hi(nx0), bf_lo(nx1), bf_hi(nx1)};
#pragma unroll
            for (int r = 0; r < 4; ++r) {
                float tg = sig2(fmaf(rg[r], an[r], xn[r]));
                float ng = fmaf(-2.0f, tg, 1.0f);
                const int i = l * 4 + r;
                hreg[i] = fmaf(zg[r], hreg[i] - ng, ng);
            }
            // write this half's h_new (bf16) to the other h buffer
            unsigned h0 = pk2(hreg[l * 4 + 0], hreg[l * 4 + 1]);
            unsigned h1 = pk2(hreg[l * 4 + 2], hreg[l * 4 + 3]);
            *(uint2*)&hB[wb + b * HB_STR + 32 * w + 16 * l + 4 * q] =
                make_uint2(h0, h1);
        }
        // 4) counted drain + barrier: step ts+1's staging (issued at ts-1)
        //    retired; this step's staging (3 newest) keeps flying.
        step_barrier_v3();
    }

    // epilogue: out[b][c] += h_d[b] . W_lin[c, d*256:+256]  (+ b_lin once)
#pragma unroll
    for (int l = 0; l < 2; ++l) {
        f32x4 v = {hreg[l * 4 + 0], hreg[l * 4 + 1],
                   hreg[l * 4 + 2], hreg[l * 4 + 3]};
        *(f32x4*)&hs[b * HS_STR + 32 * w + 16 * l + 4 * q] = v;
    }
    __syncthreads();
    if (tid < 160) {
        int bb = tid / 10;
        int c  = tid - bb * 10;
        float acc = d ? 0.0f : b_lin[c];
        const float* wl = W_lin + c * 512 + d * 256;
        const float* hp = &hs[bb * HS_STR];
        for (int i = 0; i < 256; ++i) acc += hp[i] * wl[i];
        atomicAdd(&out[(b0 + bb) * 10 + c], acc);
    }
}

// ---------------------------------------------------------------------------
extern "C" void kernel_launch(void* const* d_in, const int* in_sizes, int n_in,
                              void* d_out, int out_size, void* d_ws, size_t ws_size,
                              hipStream_t stream) {
    const int*   inp   = (const int*)d_in[0];
    const float* emb   = (const float*)d_in[1];
    const float* Wih_f = (const float*)d_in[2];
    const float* Whh_f = (const float*)d_in[3];
    const float* bih_f = (const float*)d_in[4];
    const float* bhh_f = (const float*)d_in[5];
    const float* Wih_b = (const float*)d_in[6];
    const float* Whh_b = (const float*)d_in[7];
    const float* bih_b = (const float*)d_in[8];
    const float* bhh_b = (const float*)d_in[9];
    const float* W_lin = (const float*)d_in[10];
    const float* b_lin = (const float*)d_in[11];
    float* out = (float*)d_out;
    unsigned short* G = (unsigned short*)d_ws;   // 30000*1536*2 B = 92.16 MB

    hipMemsetAsync(d_out, 0, (size_t)out_size * sizeof(float), stream);
    hipLaunchKernelGGL(gru_table_kernel, dim3(2, 128), dim3(512), 0, stream,
                       emb, Wih_f, bih_f, bhh_f, Wih_b, bih_b, bhh_b, G);
    hipLaunchKernelGGL(gru_rnn_kernel, dim3(16), dim3(512), 0, stream,
                       inp, Whh_f, bhh_f, Whh_b, bhh_b, W_lin, b_lin, G, out);
}

// Round 6
// 1448.201 us; speedup vs baseline: 1.6351x; 1.3127x over previous
//
#include <hip/hip_runtime.h>

// ---------------------------------------------------------------------------
// Bidirectional GRU (B=128, T=512, E=H=256) + linear head.
// Phase 1 (R18 = R17/R16, verified): gate table, per-thread 48 B chunks:
//   elem = d*768 + ((w*4+q)*24) + slot + r; slot: xr0:0 xz0:4 xr1:8 xz1:12
//   xn0:16 xn1:20.  Each dir-half of a token row is contiguous 1536 B.
// Phase 2 (R18): R12's EXACT schedule (double-buffered xgS, stage step ts+1
//   at top of step ts, plain __syncthreads barrier, gate-major MFMA) with
//   the compact layout's staging (3x16B global_load_lds per wave = 3 KB
//   pair-contiguous, 25% less than R12's 4 KB) and R14's verified register
//   decode (xr/xz fold into MFMA acc-init; 3x uint4 LDS reads).
//   No inline asm, no sched_barriers, no ring: those all regressed.
// ---------------------------------------------------------------------------

typedef float f32x4 __attribute__((ext_vector_type(4)));
typedef short s16x8 __attribute__((ext_vector_type(8)));

#define VOCAB   30000
#define GCOLS   1536
#define HB_STR  280     // bf16 elems per h/emb row (560 B)
#define HBUF    (16 * HB_STR)
#define HS_STR  260     // f32 elems per h row for epilogue
#define PAIR_STR 1544   // bf16 elems per batch-PAIR row (2x768 + 8 pad)
#define XGBUF   (8 * PAIR_STR)
#define SRF     (-1.4426950408889634f)   // -log2(e), sigmoid gates
#define SNF     (2.8853900817779268f)    // 2*log2(e), tanh gate

#if defined(__has_builtin)
#if __has_builtin(__builtin_amdgcn_cvt_pk_bf16_f32)
#define HAVE_PK 1
#endif
#endif

static __device__ __forceinline__ unsigned short f2bf(float f) {
    unsigned u = __builtin_bit_cast(unsigned, f);
    u += 0x7fffu + ((u >> 16) & 1u);            // RNE
    return (unsigned short)(u >> 16);
}
#ifdef HAVE_PK
typedef __bf16 bf16x2_t __attribute__((ext_vector_type(2)));
static __device__ __forceinline__ unsigned pk2(float a, float b) {
    bf16x2_t v = __builtin_amdgcn_cvt_pk_bf16_f32(a, b);
    return __builtin_bit_cast(unsigned, v);
}
#else
static __device__ __forceinline__ unsigned pk2(float a, float b) {
    return (unsigned)f2bf(a) | ((unsigned)f2bf(b) << 16);
}
#endif
static __device__ __forceinline__ float bf_lo(unsigned v) {
    return __builtin_bit_cast(float, v << 16);
}
static __device__ __forceinline__ float bf_hi(unsigned v) {
    return __builtin_bit_cast(float, v & 0xffff0000u);
}
static __device__ __forceinline__ s16x8 pack_bf8(float4 a, float4 b, float s) {
    union { s16x8 v; unsigned u[4]; } r;
    r.u[0] = pk2(a.x * s, a.y * s); r.u[1] = pk2(a.z * s, a.w * s);
    r.u[2] = pk2(b.x * s, b.y * s); r.u[3] = pk2(b.z * s, b.w * s);
    return r.v;
}
static __device__ __forceinline__ f32x4 mfma16(s16x8 a, s16x8 b, f32x4 c) {
    return __builtin_amdgcn_mfma_f32_16x16x32_bf16(a, b, c, 0, 0, 0);
}
static __device__ __forceinline__ float sig2(float x) {      // 1/(1+2^x)
    return __builtin_amdgcn_rcpf(1.0f + __builtin_amdgcn_exp2f(x));
}
static __device__ __forceinline__ void gload_lds16(const unsigned short* g, unsigned short* l) {
    __builtin_amdgcn_global_load_lds(
        (const __attribute__((address_space(1))) unsigned*)g,
        (__attribute__((address_space(3))) unsigned*)l, 16, 0, 0);
}

// ---------------------------------------------------------------------------
// Phase 1: gate table (verified, unchanged from R17/R16).
// ---------------------------------------------------------------------------
__global__ __launch_bounds__(512, 2)
void gru_table_kernel(const float* __restrict__ emb,
                      const float* __restrict__ Wih_f, const float* __restrict__ bih_f,
                      const float* __restrict__ bhh_f,
                      const float* __restrict__ Wih_b, const float* __restrict__ bih_b,
                      const float* __restrict__ bhh_b,
                      unsigned short* __restrict__ G) {
    __shared__ unsigned short aS[2][16 * HB_STR];    // dbuf emb tile (bf16)

    const int tid  = threadIdx.x;
    const int lane = tid & 63;
    const int w    = tid >> 6;       // wave 0..7
    const int u    = lane & 15;
    const int q    = lane >> 4;
    const int d    = blockIdx.x;     // 0 fwd, 1 bwd
    const int by   = blockIdx.y;     // 0..127

    const float* Wih = d ? Wih_b : Wih_f;
    const float* bih = d ? bih_b : bih_f;
    const float* bhh = d ? bhh_b : bhh_f;

    s16x8 breg[48];
    float beta[6];
#pragma unroll
    for (int t = 0; t < 6; ++t) {
        const int orig = (t >> 1) * 256 + 32 * w + ((t & 1) << 4) + u;
        const float scl = (t < 4) ? SRF : SNF;
        beta[t] = (bih[orig] + ((t < 4) ? bhh[orig] : 0.0f)) * scl;
#pragma unroll
        for (int kt = 0; kt < 8; ++kt) {
            const float* p = Wih + orig * 256 + kt * 32 + q * 8;
            breg[t * 8 + kt] =
                pack_bf8(*(const float4*)p, *(const float4*)(p + 4), scl);
        }
    }

    const int srow = tid >> 5;
    const int sc8  = (tid & 31) * 8;

    {
        const float* p = emb + (size_t)(by * 16 + srow) * 256 + sc8;
        float4 e0 = *(const float4*)p, e1 = *(const float4*)(p + 4);
        unsigned* dp = (unsigned*)&aS[0][srow * HB_STR + sc8];
        dp[0] = pk2(e0.x, e0.y); dp[1] = pk2(e0.z, e0.w);
        dp[2] = pk2(e1.x, e1.y); dp[3] = pk2(e1.z, e1.w);
    }
    __syncthreads();

    const int ubase = ((d * 8 + w) * 4 + (u >> 2)) * 24 + (u & 3);

    for (int i = 0;; ++i) {
        const int mt = by + i * 128;
        if (mt >= 1875) break;
        const int mtn = mt + 128;
        const bool has_next = (mtn < 1875);
        const int buf = i & 1;

        float4 e0, e1;
        if (has_next) {
            const float* p = emb + (size_t)(mtn * 16 + srow) * 256 + sc8;
            e0 = *(const float4*)p;
            e1 = *(const float4*)(p + 4);
        }

        const int v0 = mt * 16;
#pragma unroll
        for (int l = 0; l < 2; ++l) {
            f32x4 a0 = {0.f, 0.f, 0.f, 0.f}, a1 = a0, a2 = a0;
#pragma unroll
            for (int kt = 0; kt < 8; ++kt) {
                s16x8 af = *(const s16x8*)&aS[buf][u * HB_STR + kt * 32 + q * 8];
                a0 = mfma16(af, breg[(0 + l) * 8 + kt], a0);
                a1 = mfma16(af, breg[(2 + l) * 8 + kt], a1);
                a2 = mfma16(af, breg[(4 + l) * 8 + kt], a2);
            }
#pragma unroll
            for (int g = 0; g < 3; ++g) {
                const f32x4 a = (g == 0) ? a0 : (g == 1) ? a1 : a2;
                const int t    = 2 * g + l;
                const int slot = (g < 2) ? (8 * l + 4 * g) : (16 + 4 * l);
                unsigned short* gp =
                    G + (size_t)(v0 + q * 4) * GCOLS + ubase + slot;
#pragma unroll
                for (int r = 0; r < 4; ++r)
                    gp[(size_t)r * GCOLS] = f2bf(a[r] + beta[t]);
            }
        }
        if (has_next) {
            unsigned* dp = (unsigned*)&aS[buf ^ 1][srow * HB_STR + sc8];
            dp[0] = pk2(e0.x, e0.y); dp[1] = pk2(e0.z, e0.w);
            dp[2] = pk2(e1.x, e1.y); dp[3] = pk2(e1.z, e1.w);
        }
        __syncthreads();
    }
}

// ---------------------------------------------------------------------------
// Phase 2: recurrence. grid = 16 (dir = bx>>3, batch group = bx&7), 512 thr.
// R12 schedule; compact-layout staging (3 KB/wave/step as 3x16B loads into
// a pair-contiguous LDS region); R14 register decode.
// ---------------------------------------------------------------------------

// Stage step SP's two batch rows (2w, 2w+1; 3 KB contiguous in LDS) for the
// next step into buffer BUF. Linear LDS dest (wave-uniform base + lane*16).
#define STAGE(BUF, SP)                                                        \
    {                                                                         \
        const int s_  = ((SP) < 511) ? (SP) : 511;                            \
        const int tt_ = d ? 511 - s_ : s_;                                    \
        const unsigned short* rA =                                            \
            G + (size_t)toks[2 * w][tt_] * GCOLS + d * 768;                   \
        const unsigned short* rB =                                            \
            G + (size_t)toks[2 * w + 1][tt_] * GCOLS + d * 768;               \
        gload_lds16(rA + lane * 8, &xgS[BUF][w * PAIR_STR]);                  \
        const unsigned short* s1 =                                            \
            (lane < 32) ? rA + 512 + lane * 8 : rB + (lane - 32) * 8;         \
        gload_lds16(s1, &xgS[BUF][w * PAIR_STR + 512]);                       \
        gload_lds16(rB + 256 + lane * 8, &xgS[BUF][w * PAIR_STR + 1024]);     \
    }

__global__ __launch_bounds__(512, 2)
void gru_rnn_kernel(const int* __restrict__ inp,
                    const float* __restrict__ Whh_f, const float* __restrict__ bhh_f,
                    const float* __restrict__ Whh_b, const float* __restrict__ bhh_b,
                    const float* __restrict__ W_lin, const float* __restrict__ b_lin,
                    const unsigned short* __restrict__ G,
                    float* __restrict__ out) {
    __shared__ int            toks[16][513];          // 32.8 KB
    __shared__ unsigned short xgS[2][XGBUF];          // 49.4 KB dbuf xg (bf16)
    __shared__ unsigned short hB[2 * HBUF];           // 17.9 KB dbuf h (bf16)
    __shared__ float          bhnS[256];              // 1 KB
    __shared__ float          hs[16 * HS_STR];        // 16.6 KB epilogue

    const int tid  = threadIdx.x;
    const int lane = tid & 63;
    const int w    = tid >> 6;          // wave 0..7 (owns cols [32w,32w+32))
    const int b    = lane & 15;         // batch within group
    const int q    = lane >> 4;
    const int d    = blockIdx.x >> 3;   // 0 fwd, 1 bwd
    const int b0   = (blockIdx.x & 7) * 16;

    const float* Whh = d ? Whh_b : Whh_f;
    const float* bhh = d ? bhh_b : bhh_f;

    // W_hh as 48 A-fragments (pre-scaled): tile t = 2*gate + half.
    s16x8 wreg[48];
#pragma unroll
    for (int t = 0; t < 6; ++t) {
        const int orig = (t >> 1) * 256 + 32 * w + ((t & 1) << 4) + b;
        const float scl = (t < 4) ? SRF : SNF;
#pragma unroll
        for (int kt = 0; kt < 8; ++kt) {
            const float* p = Whh + orig * 256 + kt * 32 + q * 8;
            wreg[t * 8 + kt] =
                pack_bf8(*(const float4*)p, *(const float4*)(p + 4), scl);
        }
    }

    for (int i = tid; i < 16 * 512; i += 512) {
        int bb = i >> 9, t = i & 511;
        toks[bb][t] = inp[(b0 + bb) * 512 + t];
    }
    for (int i = tid; i < 2 * HBUF; i += 512) hB[i] = 0;   // h0 = 0
    if (tid < 256) bhnS[tid] = SNF * bhh[512 + tid];
    __syncthreads();

    // prologue: stage step-0 xg into xgS[0]
    STAGE(0, 0);
    __syncthreads();   // drains vmcnt -> xgS[0] valid

    const int hbq = b * HB_STR + q * 8;
    // consumer offsets (elems): batch b -> pair b>>1, sub-row b&1
    const int xo0 = (b >> 1) * PAIR_STR + (b & 1) * 768 + (w * 4 + q) * 24;

    float hreg[8];
#pragma unroll
    for (int i = 0; i < 8; ++i) hreg[i] = 0.f;

#pragma unroll 2
    for (int ts = 0; ts < 512; ++ts) {
        const int rb = (ts & 1) * HBUF;
        const int pn = (ts + 1) & 1;
        // 1) issue NEXT step's staging (async; drained by this step's barrier)
        STAGE(pn, ts + 1);

        // 2) read this step's xg (staged last step -> ready now); fold
        //    xr/xz into acc-inits, keep xn packed (verified R14 decode)
        const unsigned short* xs = &xgS[ts & 1][xo0];
        const uint4 p0 = *(const uint4*)(xs);
        const uint4 p1 = *(const uint4*)(xs + 8);
        const uint4 nn = *(const uint4*)(xs + 16);
        f32x4 arI0 = {bf_lo(p0.x), bf_hi(p0.x), bf_lo(p0.y), bf_hi(p0.y)};
        f32x4 azI0 = {bf_lo(p0.z), bf_hi(p0.z), bf_lo(p0.w), bf_hi(p0.w)};
        f32x4 arI1 = {bf_lo(p1.x), bf_hi(p1.x), bf_lo(p1.y), bf_hi(p1.y)};
        f32x4 azI1 = {bf_lo(p1.z), bf_hi(p1.z), bf_lo(p1.w), bf_hi(p1.w)};

        // 3) two column-halves, gate-major schedule (R12)
#pragma unroll
        for (int l = 0; l < 2; ++l) {
            f32x4 ar = l ? arI1 : arI0;
            f32x4 az = l ? azI1 : azI0;
            __builtin_amdgcn_s_setprio(1);
            // pass A: r and z gates (16 MFMA, 2 independent chains)
#pragma unroll
            for (int kt = 0; kt < 8; ++kt) {
                s16x8 hf = *(const s16x8*)&hB[rb + hbq + kt * 32];
                ar = mfma16(wreg[(0 + l) * 8 + kt], hf, ar);
                az = mfma16(wreg[(2 + l) * 8 + kt], hf, az);
            }
            // pass B: n gate (8 MFMA) — rg/zg trans overlap its drain
            f32x4 an = *(const f32x4*)&bhnS[32 * w + 16 * l + 4 * q];
#pragma unroll
            for (int kt = 0; kt < 8; ++kt) {
                s16x8 hf = *(const s16x8*)&hB[rb + hbq + kt * 32];
                an = mfma16(wreg[(4 + l) * 8 + kt], hf, an);
            }
            __builtin_amdgcn_s_setprio(0);

            float rg[4], zg[4];
#pragma unroll
            for (int r = 0; r < 4; ++r) {
                rg[r] = sig2(ar[r]);
                zg[r] = sig2(az[r]);
            }
            const unsigned nx0 = l ? nn.z : nn.x;
            const unsigned nx1 = l ? nn.w : nn.y;
            const float xn[4] = {bf_lo(nx0), bf_hi(nx0), bf_lo(nx1), bf_hi(nx1)};
#pragma unroll
            for (int r = 0; r < 4; ++r) {
                float tg = sig2(fmaf(rg[r], an[r], xn[r]));
                float ng = fmaf(-2.0f, tg, 1.0f);
                const int i = l * 4 + r;
                hreg[i] = fmaf(zg[r], hreg[i] - ng, ng);
            }
            // write this half's h_new (bf16) to the other h buffer
            unsigned h0 = pk2(hreg[l * 4 + 0], hreg[l * 4 + 1]);
            unsigned h1 = pk2(hreg[l * 4 + 2], hreg[l * 4 + 3]);
            *(uint2*)&hB[pn * HBUF + b * HB_STR + 32 * w + 16 * l + 4 * q] =
                make_uint2(h0, h1);
        }
        // 4) one barrier: drains lgkm (h writes) + vmcnt (xg stage) together
        __syncthreads();
    }

    // epilogue: out[b][c] += h_d[b] . W_lin[c, d*256:+256]  (+ b_lin once)
#pragma unroll
    for (int l = 0; l < 2; ++l) {
        f32x4 v = {hreg[l * 4 + 0], hreg[l * 4 + 1],
                   hreg[l * 4 + 2], hreg[l * 4 + 3]};
        *(f32x4*)&hs[b * HS_STR + 32 * w + 16 * l + 4 * q] = v;
    }
    __syncthreads();
    if (tid < 160) {
        int bb = tid / 10;
        int c  = tid - bb * 10;
        float acc = d ? 0.0f : b_lin[c];
        const float* wl = W_lin + c * 512 + d * 256;
        const float* hp = &hs[bb * HS_STR];
        for (int i = 0; i < 256; ++i) acc += hp[i] * wl[i];
        atomicAdd(&out[(b0 + bb) * 10 + c], acc);
    }
}

// ---------------------------------------------------------------------------
extern "C" void kernel_launch(void* const* d_in, const int* in_sizes, int n_in,
                              void* d_out, int out_size, void* d_ws, size_t ws_size,
                              hipStream_t stream) {
    const int*   inp   = (const int*)d_in[0];
    const float* emb   = (const float*)d_in[1];
    const float* Wih_f = (const float*)d_in[2];
    const float* Whh_f = (const float*)d_in[3];
    const float* bih_f = (const float*)d_in[4];
    const float* bhh_f = (const float*)d_in[5];
    const float* Wih_b = (const float*)d_in[6];
    const float* Whh_b = (const float*)d_in[7];
    const float* bih_b = (const float*)d_in[8];
    const float* bhh_b = (const float*)d_in[9];
    const float* W_lin = (const float*)d_in[10];
    const float* b_lin = (const float*)d_in[11];
    float* out = (float*)d_out;
    unsigned short* G = (unsigned short*)d_ws;   // 30000*1536*2 B = 92.16 MB

    hipMemsetAsync(d_out, 0, (size_t)out_size * sizeof(float), stream);
    hipLaunchKernelGGL(gru_table_kernel, dim3(2, 128), dim3(512), 0, stream,
                       emb, Wih_f, bih_f, bhh_f, Wih_b, bih_b, bhh_b, G);
    hipLaunchKernelGGL(gru_rnn_kernel, dim3(16), dim3(512), 0, stream,
                       inp, Whh_f, bhh_f, Whh_b, bhh_b, W_lin, b_lin, G, out);
}